// Round 9
// baseline (138.170 us; speedup 1.0000x reference)
//
#include <hip/hip_runtime.h>
#include <math.h>

#define P 7
#define SCALE 0.125f
#define BB 4
#define CC 256
#define HH 128
#define WW 128
#define KK 512
#define NBIN 49
#define GPB 13            // bin-groups per ROI (4 bins each, 13*4 >= 49)
#define NXCD 8

#define TRANS_BLOCKS 4096   // (HH*WW/64) * (CC/64) * BB = 256*4*4
#define MASK_BLOCKS  4096   // KK*HH rows / 16 waves per block

__device__ __forceinline__ unsigned short f32_to_bf16_rne(float f) {
    unsigned int u = __float_as_uint(f);
    u += 0x7FFFu + ((u >> 16) & 1u);
    return (unsigned short)(u >> 16);
}

// Order-preserving bf16 -> u16 key. key 0 reserved = "empty/masked".
__device__ __forceinline__ unsigned short bf16_key(unsigned short b) {
    return (b & 0x8000u) ? (unsigned short)(~b) : (unsigned short)(b | 0x8000u);
}

__device__ __forceinline__ unsigned int pkmax_u16(unsigned int a, unsigned int b) {
    unsigned int d;
    asm("v_pk_max_u16 %0, %1, %2" : "=v"(d) : "v"(a), "v"(b));
    return d;
}

// ---- Fused prep: transpose+convert AND mask->bitmask in one launch ----
// blocks [0, TRANS_BLOCKS): [B,C,H,W] f32 -> [B,H*W,C] u16 keys
// blocks [TRANS_BLOCKS, +MASK_BLOCKS): [K,H,W] f32 -> [K,H] 2xu64
__global__ __launch_bounds__(1024) void prep_fused(
    const float* __restrict__ in, const float* __restrict__ masks,
    unsigned short* __restrict__ out, unsigned long long* __restrict__ mbits)
{
    __shared__ float tile[64][65];    // tile[channel][pixel]
    const int bid = blockIdx.x;
    const int tid = threadIdx.x;

    if (bid < TRANS_BLOCKS) {
        const int p0 = (bid & 255) * 64;        // pixel tile
        const int c0 = ((bid >> 8) & 3) * 64;   // channel tile
        const int b  = bid >> 10;               // batch
        const int tx = tid & 63;
        const int ty = tid >> 6;                // 0..15

        const float* src = in + (size_t)b * CC * (HH * WW);
#pragma unroll
        for (int j = 0; j < 64; j += 16)
            tile[ty + j][tx] =
                __builtin_nontemporal_load(&src[(size_t)(c0 + ty + j) * (HH * WW) + p0 + tx]);
        __syncthreads();

        unsigned int* dst = (unsigned int*)(out + (size_t)b * (HH * WW) * CC);
#pragma unroll
        for (int i = 0; i < 2; ++i) {
            const int flat = i * 1024 + tid;
            const int px = flat >> 5;
            const int cp = flat & 31;
            const unsigned int lo = bf16_key(f32_to_bf16_rne(tile[cp * 2][px]));
            const unsigned int hi = bf16_key(f32_to_bf16_rne(tile[cp * 2 + 1][px]));
            dst[((size_t)(p0 + px) * CC + c0) / 2 + cp] = lo | (hi << 16);
        }
    } else {
        const int mbid = bid - TRANS_BLOCKS;
        const int wv   = tid >> 6;              // 0..15
        const int lane = tid & 63;
        const int row  = mbid * 16 + wv;        // 0 .. KK*HH-1
        const float* mr = masks + (size_t)row * WW;
        const unsigned long long b0 = __ballot(mr[lane] > 0.5f);
        const unsigned long long b1 = __ballot(mr[64 + lane] > 0.5f);
        if (lane == 0) {
            mbits[(size_t)row * 2]     = b0;
            mbits[(size_t)row * 2 + 1] = b1;
        }
    }
}

// ---- Pool: one wave per bin, 8-px chunks, imm-offset loads, u32 addressing --
__global__ __launch_bounds__(256) void pool_key(
    const unsigned int* __restrict__ fbase,         // [B,HW,C/2] packed keys
    const float* __restrict__ rois,                 // [K,5]
    const unsigned long long* __restrict__ mbits,   // [K,H,2]
    float* __restrict__ out)                        // [K,C,P,P]
{
    // XCD-aware swizzle: all GPB blocks of ROI k land on XCD k%8
    const int pid = blockIdx.x;
    const int x   = pid & (NXCD - 1);
    const int t   = pid >> 3;
    const int g   = t % GPB;
    const int q   = t / GPB;
    const int k   = q * NXCD + x;

    const int wv   = threadIdx.x >> 6;
    const int lane = threadIdx.x & 63;
    const int bi   = g * 4 + wv;
    if (bi >= NBIN) return;                 // wave-uniform
    const int ph = bi / P;
    const int pw = bi % P;

    const int half = lane >> 5;             // even/odd pixel of each pair
    const int c4   = (lane & 31) * 4;       // uint offset: 8 channels
    const unsigned int lane_off = (unsigned int)(half * (CC / 2) + c4);

    const float* roi = rois + k * 5;
    const int b  = (int)roi[0];
    const int sw = (int)rintf(roi[1] * SCALE);
    const int sh = (int)rintf(roi[2] * SCALE);
    const int ew = (int)rintf(roi[3] * SCALE);
    const int eh = (int)rintf(roi[4] * SCALE);
    const int roi_w = max(ew - sw + 1, 1);
    const int roi_h = max(eh - sh + 1, 1);

    const int hs = min(max((ph * roi_h) / P + sh, 0), HH);
    const int he = min(max(((ph + 1) * roi_h + P - 1) / P + sh, 0), HH);
    const int wl = min(max((pw * roi_w) / P + sw, 0), WW);
    const int wr = min(max(((pw + 1) * roi_w + P - 1) / P + sw, 0), WW);

    const unsigned int boff = (unsigned int)b * (HH * WW * (CC / 2));
    const unsigned long long* mrow = mbits + (size_t)k * HH * 2;

    unsigned int a0 = 0, a1 = 0, a2 = 0, a3 = 0;   // packed key accumulators

#pragma unroll 2
    for (int h = hs; h < he; ++h) {
        const unsigned long long lo = mrow[h * 2];
        const unsigned long long hi = mrow[h * 2 + 1];
        const unsigned int rowoff = boff + (unsigned int)h * (WW * (CC / 2));
        for (int w0 = wl; w0 < wr; w0 += 8) {
            // wave-uniform 8-bit mask chunk for pixels w0..w0+7 (SALU)
            unsigned long long sh64;
            if (w0 >= 64)      sh64 = hi >> (w0 - 64);
            else if (w0 == 0)  sh64 = lo;
            else               sh64 = (lo >> w0) | (hi << (64 - w0));
            unsigned int chunk = (unsigned int)(sh64 & 0xFFu);
            const int n = wr - w0;                     // valid pixel count
            chunk &= (n >= 8) ? 0xFFu : ((1u << n) - 1u);

            // one per-lane base; pixel pairs at immediate offsets (1 KB apart).
            // Over-reads past wr are harmless (masked off; memory valid: mbits
            // region follows the key buffer in the workspace).
            const unsigned int base = rowoff + (unsigned int)w0 * (CC / 2) + lane_off;
            const uint4 kv0 = *(const uint4*)(fbase + base);
            const uint4 kv1 = *(const uint4*)(fbase + base + 256);
            const uint4 kv2 = *(const uint4*)(fbase + base + 512);
            const uint4 kv3 = *(const uint4*)(fbase + base + 768);

            uint4 kv[4] = {kv0, kv1, kv2, kv3};
#pragma unroll
            for (int p = 0; p < 4; ++p) {
                const unsigned int sel = (chunk >> (p * 2 + half)) & 1u;
                const unsigned int msk = 0u - sel;     // 0 or ~0
                a0 = pkmax_u16(a0, kv[p].x & msk);
                a1 = pkmax_u16(a1, kv[p].y & msk);
                a2 = pkmax_u16(a2, kv[p].z & msk);
                a3 = pkmax_u16(a3, kv[p].w & msk);
            }
        }
    }

    // combine pixel-halves (lane i <-> i+32 hold same channels)
    a0 = pkmax_u16(a0, (unsigned int)__shfl_xor((int)a0, 32, 64));
    a1 = pkmax_u16(a1, (unsigned int)__shfl_xor((int)a1, 32, 64));
    a2 = pkmax_u16(a2, (unsigned int)__shfl_xor((int)a2, 32, 64));
    a3 = pkmax_u16(a3, (unsigned int)__shfl_xor((int)a3, 32, 64));

    if (half == 0) {
        const unsigned int acc[4] = {a0, a1, a2, a3};
        float* o = out + ((size_t)k * CC + (size_t)c4 * 2) * NBIN + ph * P + pw;
#pragma unroll
        for (int j = 0; j < 8; ++j) {
            const unsigned int d = acc[j >> 1];
            const unsigned int key = (j & 1) ? (d >> 16) : (d & 0xFFFFu);
            float r;
            if (key == 0u) {
                r = 0.0f;                       // empty / fully-masked bin
            } else {
                const unsigned int bbits =
                    (key & 0x8000u) ? (key ^ 0x8000u) : (~key & 0xFFFFu);
                r = __uint_as_float(bbits << 16);
            }
            o[(size_t)j * NBIN] = r;
        }
    }
}

// ---------- Fallback (NCHW direct, correctness-only path) ----------
__global__ __launch_bounds__(256) void ROIPool_nchw_kernel(
    const float* __restrict__ inputs, const float* __restrict__ rois,
    const float* __restrict__ masks, float* __restrict__ out)
{
    const int k  = blockIdx.x;
    const int ph = blockIdx.y;
    const int c  = threadIdx.x;

    const float* roi = rois + k * 5;
    const int b  = (int)roi[0];
    const int sw = (int)rintf(roi[1] * SCALE);
    const int sh = (int)rintf(roi[2] * SCALE);
    const int ew = (int)rintf(roi[3] * SCALE);
    const int eh = (int)rintf(roi[4] * SCALE);
    const int roi_w = max(ew - sw + 1, 1);
    const int roi_h = max(eh - sh + 1, 1);

    const int hs = min(max((ph * roi_h) / P + sh, 0), HH);
    const int he = min(max(((ph + 1) * roi_h + P - 1) / P + sh, 0), HH);

    int wsb[P], web[P];
#pragma unroll
    for (int pw = 0; pw < P; ++pw) {
        wsb[pw] = min(max((pw * roi_w) / P + sw, 0), WW);
        web[pw] = min(max(((pw + 1) * roi_w + P - 1) / P + sw, 0), WW);
    }

    const float* f = inputs + ((size_t)b * CC + c) * (HH * WW);
    const float* m = masks  + (size_t)k * (HH * WW);

    float vmax[P];
#pragma unroll
    for (int pw = 0; pw < P; ++pw) vmax[pw] = -INFINITY;

    for (int h = hs; h < he; ++h) {
        const float* frow = f + h * WW;
        const float* mrow = m + h * WW;
#pragma unroll
        for (int pw = 0; pw < P; ++pw) {
            float v = vmax[pw];
            for (int w = wsb[pw]; w < web[pw]; ++w)
                if (mrow[w] > 0.5f) v = fmaxf(v, frow[w]);
            vmax[pw] = v;
        }
    }

    float* o = out + (((size_t)k * CC + c) * P + ph) * P;
#pragma unroll
    for (int pw = 0; pw < P; ++pw) {
        const float v = vmax[pw];
        o[pw] = isinf(v) ? 0.0f : v;
    }
}

extern "C" void kernel_launch(void* const* d_in, const int* in_sizes, int n_in,
                              void* d_out, int out_size, void* d_ws, size_t ws_size,
                              hipStream_t stream) {
    const float* inputs = (const float*)d_in[0];
    const float* rois   = (const float*)d_in[1];
    const float* masks  = (const float*)d_in[2];
    float* out = (float*)d_out;

    const size_t keys_bytes  = (size_t)BB * CC * HH * WW * sizeof(unsigned short); // 32 MiB
    const size_t mbits_bytes = (size_t)KK * HH * 2 * sizeof(unsigned long long);   // 1 MiB

    if (ws_size >= keys_bytes + mbits_bytes) {
        unsigned short* fT = (unsigned short*)d_ws;
        unsigned long long* mb = (unsigned long long*)((char*)d_ws + keys_bytes);
        {
            dim3 grid(TRANS_BLOCKS + MASK_BLOCKS);
            dim3 block(1024);
            prep_fused<<<grid, block, 0, stream>>>(inputs, masks, fT, mb);
        }
        {
            dim3 grid(KK * GPB);
            dim3 block(256);
            pool_key<<<grid, block, 0, stream>>>((const unsigned int*)fT, rois, mb, out);
        }
    } else {
        dim3 grid(KK, P);
        dim3 block(CC);
        ROIPool_nchw_kernel<<<grid, block, 0, stream>>>(inputs, rois, masks, out);
    }
}

// Round 10
// 119.033 us; speedup vs baseline: 1.1608x; 1.1608x over previous
//
#include <hip/hip_runtime.h>
#include <math.h>

#define P 7
#define SCALE 0.125f
#define BB 4
#define CC 256
#define HH 128
#define WW 128
#define KK 512
#define NBIN 49
#define GPB 13            // bin-groups per ROI (4 bins each, 13*4 >= 49)
#define NXCD 8
#define RPX  (KK / NXCD)  // 64 ROIs per XCD slice

#define TRANS_BLOCKS 4096   // (HH*WW/64) * (CC/64) * BB
#define MASK_BLOCKS  4096   // KK*HH rows / 16 waves per block

__device__ __forceinline__ unsigned short f32_to_bf16_rne(float f) {
    unsigned int u = __float_as_uint(f);
    u += 0x7FFFu + ((u >> 16) & 1u);
    return (unsigned short)(u >> 16);
}

// Order-preserving bf16 -> u16 key. key 0 reserved = "empty/masked".
__device__ __forceinline__ unsigned short bf16_key(unsigned short b) {
    return (b & 0x8000u) ? (unsigned short)(~b) : (unsigned short)(b | 0x8000u);
}

__device__ __forceinline__ unsigned int pkmax_u16(unsigned int a, unsigned int b) {
    unsigned int d;
    asm("v_pk_max_u16 %0, %1, %2" : "=v"(d) : "v"(a), "v"(b));
    return d;
}

// ---- Fused prep: transpose+convert, mask->bitmask, ROI sort ----
// blocks [0, TRANS_BLOCKS): [B,C,H,W] f32 -> [B,H*W,C] u16 keys
// blocks [TRANS_BLOCKS, +MASK_BLOCKS): [K,H,W] f32 -> [K,H] 2xu64
// last block: deterministic counting sort of ROIs by (batch, start-row)
__global__ __launch_bounds__(1024) void prep_fused(
    const float* __restrict__ in, const float* __restrict__ masks,
    const float* __restrict__ rois,
    unsigned short* __restrict__ out, unsigned long long* __restrict__ mbits,
    int* __restrict__ perm)
{
    __shared__ float tile[64][65];    // tile[channel][pixel]
    const int bid = blockIdx.x;
    const int tid = threadIdx.x;

    if (bid < TRANS_BLOCKS) {
        const int p0 = (bid & 255) * 64;        // pixel tile
        const int c0 = ((bid >> 8) & 3) * 64;   // channel tile
        const int b  = bid >> 10;               // batch
        const int tx = tid & 63;
        const int ty = tid >> 6;                // 0..15

        const float* src = in + (size_t)b * CC * (HH * WW);
#pragma unroll
        for (int j = 0; j < 64; j += 16)
            tile[ty + j][tx] =
                __builtin_nontemporal_load(&src[(size_t)(c0 + ty + j) * (HH * WW) + p0 + tx]);
        __syncthreads();

        unsigned int* dst = (unsigned int*)(out + (size_t)b * (HH * WW) * CC);
#pragma unroll
        for (int i = 0; i < 2; ++i) {
            const int flat = i * 1024 + tid;
            const int px = flat >> 5;
            const int cp = flat & 31;
            const unsigned int lo = bf16_key(f32_to_bf16_rne(tile[cp * 2][px]));
            const unsigned int hi = bf16_key(f32_to_bf16_rne(tile[cp * 2 + 1][px]));
            dst[((size_t)(p0 + px) * CC + c0) / 2 + cp] = lo | (hi << 16);
        }
    } else if (bid < TRANS_BLOCKS + MASK_BLOCKS) {
        const int mbid = bid - TRANS_BLOCKS;
        const int wv   = tid >> 6;              // 0..15
        const int lane = tid & 63;
        const int row  = mbid * 16 + wv;        // 0 .. KK*HH-1
        const float* mr = masks + (size_t)row * WW;
        const unsigned long long b0 = __ballot(mr[lane] > 0.5f);
        const unsigned long long b1 = __ballot(mr[64 + lane] > 0.5f);
        if (lane == 0) {
            mbits[(size_t)row * 2]     = b0;
            mbits[(size_t)row * 2 + 1] = b1;
        }
    } else {
        // deterministic rank sort of 512 ROIs by key=(batch,row-start)
        __shared__ int skey[KK];
        if (tid < KK) {
            const float* r = rois + (size_t)tid * 5;
            const int b  = (int)r[0];
            int sh = (int)rintf(r[2] * SCALE);
            sh = min(max(sh, 0), HH - 1);
            skey[tid] = b * HH + sh;
        }
        __syncthreads();
        if (tid < KK) {
            const int mykey = skey[tid];
            int pos = 0;
            for (int j = 0; j < KK; ++j) {
                const int kj = skey[j];
                pos += (kj < mykey) || (kj == mykey && j < tid);
            }
            perm[pos] = tid;
        }
    }
}

// ---- Pool: one wave per bin, 8-px chunks, bitmask predication ----
__global__ __launch_bounds__(256) void pool_key(
    const unsigned int* __restrict__ fbase,         // [B,HW,C/2] packed keys
    const float* __restrict__ rois,                 // [K,5]
    const unsigned long long* __restrict__ mbits,   // [K,H,2]
    const int* __restrict__ perm,                   // [K] sorted ROI order
    float* __restrict__ out)                        // [K,C,P,P]
{
    // XCD x processes sorted-slice [x*64, x*64+64): same-batch, row-adjacent
    // ROIs share that XCD's L2. 13 blocks of one ROI are dispatch-adjacent.
    const int pid = blockIdx.x;
    const int x   = pid & (NXCD - 1);
    const int t   = pid >> 3;
    const int g   = t % GPB;
    const int q   = t / GPB;                // 0..63
    const int k   = perm[x * RPX + q];

    const int wv   = threadIdx.x >> 6;
    const int lane = threadIdx.x & 63;
    const int bi   = g * 4 + wv;
    if (bi >= NBIN) return;                 // wave-uniform
    const int ph = bi / P;
    const int pw = bi % P;

    const int half = lane >> 5;             // even/odd pixel of each pair
    const int c4   = (lane & 31) * 4;       // uint offset: 8 channels

    const float* roi = rois + (size_t)k * 5;
    const int b  = (int)roi[0];
    const int sw = (int)rintf(roi[1] * SCALE);
    const int sh = (int)rintf(roi[2] * SCALE);
    const int ew = (int)rintf(roi[3] * SCALE);
    const int eh = (int)rintf(roi[4] * SCALE);
    const int roi_w = max(ew - sw + 1, 1);
    const int roi_h = max(eh - sh + 1, 1);

    const int hs = min(max((ph * roi_h) / P + sh, 0), HH);
    const int he = min(max(((ph + 1) * roi_h + P - 1) / P + sh, 0), HH);
    const int wl = min(max((pw * roi_w) / P + sw, 0), WW);
    const int wr = min(max(((pw + 1) * roi_w + P - 1) / P + sw, 0), WW);

    const unsigned int boff = (unsigned int)b * (HH * WW * (CC / 2));
    const unsigned long long* mrow = mbits + (size_t)k * HH * 2;

    unsigned int a0 = 0, a1 = 0, a2 = 0, a3 = 0;   // packed key accumulators

#pragma unroll 4
    for (int h = hs; h < he; ++h) {
        const unsigned long long lo = mrow[h * 2];
        const unsigned long long hi = mrow[h * 2 + 1];
        const unsigned int rowoff = boff + (unsigned int)h * (WW * (CC / 2));
        for (int w0 = wl; w0 < wr; w0 += 8) {
            // wave-uniform 8-bit mask chunk for pixels w0..w0+7
            unsigned long long sh64;
            if (w0 >= 64)      sh64 = hi >> (w0 - 64);
            else if (w0 == 0)  sh64 = lo;
            else               sh64 = (lo >> w0) | (hi << (64 - w0));
            unsigned int chunk = (unsigned int)(sh64 & 0xFFu);
            const int n = wr - w0;                     // valid pixel count
            chunk &= (n >= 8) ? 0xFFu : ((1u << n) - 1u);

            uint4 kv[4];
#pragma unroll
            for (int p = 0; p < 4; ++p) {
                // clamp to wr-1: tail loads alias the last valid pixel (L1 hit)
                const unsigned int wc = (unsigned int)min(w0 + p * 2 + half, wr - 1);
                kv[p] = *(const uint4*)(fbase + rowoff + wc * (CC / 2) + c4);
            }
#pragma unroll
            for (int p = 0; p < 4; ++p) {
                const unsigned int sel = (chunk >> (p * 2 + half)) & 1u;
                const unsigned int msk = 0u - sel;     // 0 or ~0
                a0 = pkmax_u16(a0, kv[p].x & msk);
                a1 = pkmax_u16(a1, kv[p].y & msk);
                a2 = pkmax_u16(a2, kv[p].z & msk);
                a3 = pkmax_u16(a3, kv[p].w & msk);
            }
        }
    }

    // combine pixel-halves (lane i <-> i+32 hold same channels)
    a0 = pkmax_u16(a0, (unsigned int)__shfl_xor((int)a0, 32, 64));
    a1 = pkmax_u16(a1, (unsigned int)__shfl_xor((int)a1, 32, 64));
    a2 = pkmax_u16(a2, (unsigned int)__shfl_xor((int)a2, 32, 64));
    a3 = pkmax_u16(a3, (unsigned int)__shfl_xor((int)a3, 32, 64));

    if (half == 0) {
        const unsigned int acc[4] = {a0, a1, a2, a3};
        float* o = out + ((size_t)k * CC + (size_t)c4 * 2) * NBIN + ph * P + pw;
#pragma unroll
        for (int j = 0; j < 8; ++j) {
            const unsigned int d = acc[j >> 1];
            const unsigned int key = (j & 1) ? (d >> 16) : (d & 0xFFFFu);
            float r;
            if (key == 0u) {
                r = 0.0f;                       // empty / fully-masked bin
            } else {
                const unsigned int bbits =
                    (key & 0x8000u) ? (key ^ 0x8000u) : (~key & 0xFFFFu);
                r = __uint_as_float(bbits << 16);
            }
            o[(size_t)j * NBIN] = r;
        }
    }
}

// ---------- Fallback (NCHW direct, correctness-only path) ----------
__global__ __launch_bounds__(256) void ROIPool_nchw_kernel(
    const float* __restrict__ inputs, const float* __restrict__ rois,
    const float* __restrict__ masks, float* __restrict__ out)
{
    const int k  = blockIdx.x;
    const int ph = blockIdx.y;
    const int c  = threadIdx.x;

    const float* roi = rois + k * 5;
    const int b  = (int)roi[0];
    const int sw = (int)rintf(roi[1] * SCALE);
    const int sh = (int)rintf(roi[2] * SCALE);
    const int ew = (int)rintf(roi[3] * SCALE);
    const int eh = (int)rintf(roi[4] * SCALE);
    const int roi_w = max(ew - sw + 1, 1);
    const int roi_h = max(eh - sh + 1, 1);

    const int hs = min(max((ph * roi_h) / P + sh, 0), HH);
    const int he = min(max(((ph + 1) * roi_h + P - 1) / P + sh, 0), HH);

    int wsb[P], web[P];
#pragma unroll
    for (int pw = 0; pw < P; ++pw) {
        wsb[pw] = min(max((pw * roi_w) / P + sw, 0), WW);
        web[pw] = min(max(((pw + 1) * roi_w + P - 1) / P + sw, 0), WW);
    }

    const float* f = inputs + ((size_t)b * CC + c) * (HH * WW);
    const float* m = masks  + (size_t)k * (HH * WW);

    float vmax[P];
#pragma unroll
    for (int pw = 0; pw < P; ++pw) vmax[pw] = -INFINITY;

    for (int h = hs; h < he; ++h) {
        const float* frow = f + h * WW;
        const float* mrow = m + h * WW;
#pragma unroll
        for (int pw = 0; pw < P; ++pw) {
            float v = vmax[pw];
            for (int w = wsb[pw]; w < web[pw]; ++w)
                if (mrow[w] > 0.5f) v = fmaxf(v, frow[w]);
            vmax[pw] = v;
        }
    }

    float* o = out + (((size_t)k * CC + c) * P + ph) * P;
#pragma unroll
    for (int pw = 0; pw < P; ++pw) {
        const float v = vmax[pw];
        o[pw] = isinf(v) ? 0.0f : v;
    }
}

extern "C" void kernel_launch(void* const* d_in, const int* in_sizes, int n_in,
                              void* d_out, int out_size, void* d_ws, size_t ws_size,
                              hipStream_t stream) {
    const float* inputs = (const float*)d_in[0];
    const float* rois   = (const float*)d_in[1];
    const float* masks  = (const float*)d_in[2];
    float* out = (float*)d_out;

    const size_t keys_bytes  = (size_t)BB * CC * HH * WW * sizeof(unsigned short); // 32 MiB
    const size_t mbits_bytes = (size_t)KK * HH * 2 * sizeof(unsigned long long);   // 1 MiB
    const size_t perm_bytes  = (size_t)KK * sizeof(int);                           // 2 KiB

    if (ws_size >= keys_bytes + mbits_bytes + perm_bytes) {
        unsigned short* fT = (unsigned short*)d_ws;
        unsigned long long* mb = (unsigned long long*)((char*)d_ws + keys_bytes);
        int* perm = (int*)((char*)d_ws + keys_bytes + mbits_bytes);
        {
            dim3 grid(TRANS_BLOCKS + MASK_BLOCKS + 1);
            dim3 block(1024);
            prep_fused<<<grid, block, 0, stream>>>(inputs, masks, rois, fT, mb, perm);
        }
        {
            dim3 grid(KK * GPB);
            dim3 block(256);
            pool_key<<<grid, block, 0, stream>>>((const unsigned int*)fT, rois, mb, perm, out);
        }
    } else {
        dim3 grid(KK, P);
        dim3 block(CC);
        ROIPool_nchw_kernel<<<grid, block, 0, stream>>>(inputs, rois, masks, out);
    }
}